// Round 1
// 369.984 us; speedup vs baseline: 1.1047x; 1.1047x over previous
//
#include <hip/hip_runtime.h>

typedef _Float16 f16;
typedef __attribute__((ext_vector_type(8))) _Float16 half8;
typedef __attribute__((ext_vector_type(4))) _Float16 half4v;
typedef __attribute__((ext_vector_type(4))) float floatx4;

#define T_DIM 2048
#define HID   2048
#define NH    16
#define HD    128
#define QG_LD 2064
#define SM_SCALE 0.08838834764831845f   // 1/sqrt(128)
#define NEG_BIG  -1e30f

// ---------------------------------------------------------------- async copy
__device__ __forceinline__ void async16(const void* g, void* l) {
  __builtin_amdgcn_global_load_lds((const __attribute__((address_space(1))) void*)g,
                                   (__attribute__((address_space(3))) void*)l, 16, 0, 0);
}

// ------------------------------------------------- fused QKV weight transpose (z selects)
__global__ __launch_bounds__(256) void transpose_all(const float* __restrict__ Wq,
                                                     const float* __restrict__ Wk,
                                                     const float* __restrict__ Wv,
                                                     f16* __restrict__ WqT, f16* __restrict__ WkT,
                                                     f16* __restrict__ WvT) {
  __shared__ float tile[32][33];
  const int z = blockIdx.z;
  const float* src = (z == 0) ? Wq : ((z == 1) ? Wk : Wv);
  const int ld = (z == 0) ? QG_LD : 2048;
  f16* dst = (z == 0) ? WqT : ((z == 1) ? WkT : WvT);
  const int bx = blockIdx.x * 32, by = blockIdx.y * 32;
  const int tx = threadIdx.x, ty = threadIdx.y;
#pragma unroll
  for (int i = 0; i < 4; ++i)
    tile[ty + 8 * i][tx] = src[(size_t)(by + ty + 8 * i) * ld + bx + tx];
  __syncthreads();
#pragma unroll
  for (int i = 0; i < 4; ++i)
    dst[(size_t)(bx + ty + 8 * i) * HID + by + tx] = (f16)tile[tx][ty + 8 * i];
}

// ------------------------------------------------- fp32 -> fp16 transpose (Wo)
__global__ __launch_bounds__(256) void transpose_w(const float* __restrict__ src, int src_ld,
                                                   f16* __restrict__ dst) {
  __shared__ float tile[32][33];
  const int bx = blockIdx.x * 32, by = blockIdx.y * 32;
  const int tx = threadIdx.x, ty = threadIdx.y;
#pragma unroll
  for (int i = 0; i < 4; ++i)
    tile[ty + 8 * i][tx] = src[(size_t)(by + ty + 8 * i) * src_ld + bx + tx];
  __syncthreads();
#pragma unroll
  for (int i = 0; i < 4; ++i)
    dst[(size_t)(bx + ty + 8 * i) * HID + by + tx] = (f16)tile[tx][ty + 8 * i];
}

// ------------------------------------------------- fp16 -> fp16 transpose (V)
__global__ __launch_bounds__(256) void transpose_h(const f16* __restrict__ src, f16* __restrict__ dst) {
  __shared__ f16 tile[32][33];
  const int bx = blockIdx.x * 32, by = blockIdx.y * 32;
  const int tx = threadIdx.x, ty = threadIdx.y;
#pragma unroll
  for (int i = 0; i < 4; ++i)
    tile[ty + 8 * i][tx] = src[(size_t)(by + ty + 8 * i) * T_DIM + bx + tx];
  __syncthreads();
#pragma unroll
  for (int i = 0; i < 4; ++i)
    dst[(size_t)(bx + ty + 8 * i) * T_DIM + by + tx] = tile[tx][ty + 8 * i];
}

// ------------------------------------------------- fp32 -> fp16 convert (hidden)
__global__ __launch_bounds__(256) void convert_f32_f16(const float* __restrict__ src, f16* __restrict__ dst) {
  const int i = (blockIdx.x * 256 + threadIdx.x) * 4;
  const float4 v = *(const float4*)(src + i);
  half4v o;
  o.x = (f16)v.x; o.y = (f16)v.y; o.z = (f16)v.z; o.w = (f16)v.w;
  *(half4v*)(dst + i) = o;
}

// ------------------------------------------------- gate: fp64 dot, sign only matters
__global__ __launch_bounds__(256) void gate_kernel(const float* __restrict__ hidden,
                                                   const float* __restrict__ Wq,
                                                   float* __restrict__ gate) {
  __shared__ double red[256][16];
  const int t = blockIdx.x, tid = threadIdx.x;
  double sums[16];
#pragma unroll
  for (int h2 = 0; h2 < 16; ++h2) sums[h2] = 0.0;
  const float* hrow = hidden + (size_t)t * HID;
  for (int k = tid; k < HID; k += 256) {
    const double hv = (double)hrow[k];
    const float* wr = Wq + (size_t)k * QG_LD + 2048;
#pragma unroll
    for (int h2 = 0; h2 < 16; ++h2) sums[h2] += hv * (double)wr[h2];
  }
#pragma unroll
  for (int h2 = 0; h2 < 16; ++h2) red[tid][h2] = sums[h2];
  __syncthreads();
  for (int st = 128; st > 0; st >>= 1) {
    if (tid < st) {
#pragma unroll
      for (int h2 = 0; h2 < 16; ++h2) red[tid][h2] += red[tid + st][h2];
    }
    __syncthreads();
  }
  if (tid < 16) gate[(size_t)t * 16 + tid] = (red[0][tid] > 0.0) ? 1.f : 0.f;
}

// ------------------------------------------------- RMSNorm(full 2048) + RoPE (q & k fused, f16 in)
__global__ __launch_bounds__(256) void norm_rope2(const f16* __restrict__ qsrc, const f16* __restrict__ ksrc,
                                                  const float* __restrict__ qw, const float* __restrict__ kw,
                                                  const int* __restrict__ pos,
                                                  f16* __restrict__ qdst, f16* __restrict__ kdst) {
  __shared__ float row[2048];
  __shared__ float red[256];
  const int t = blockIdx.x & 2047, sel = blockIdx.x >> 11, tid = threadIdx.x;
  const f16* s = (sel ? ksrc : qsrc) + (size_t)t * HID;
  const float* w = sel ? kw : qw;
  f16* dst = sel ? kdst : qdst;
  float ss = 0.f;
#pragma unroll
  for (int e = 0; e < 8; ++e) {
    float v = (float)s[tid + 256 * e];
    row[tid + 256 * e] = v;
    ss += v * v;
  }
  red[tid] = ss;
  __syncthreads();
  for (int st = 128; st > 0; st >>= 1) {
    if (tid < st) red[tid] += red[tid + st];
    __syncthreads();
  }
  const float scl = rsqrtf(red[0] * (1.f / 2048.f) + 1e-6f);
  const float p = (float)pos[t];
#pragma unroll
  for (int e = 0; e < 8; ++e) {
    const int idx = tid + 256 * e;
    const int d = idx & 127;
    const int dh = d & 63;
    const int pidx = (d < 64) ? idx + 64 : idx - 64;
    const float xn = row[idx] * scl * w[idx];
    const float xp = row[pidx] * scl * w[pidx];
    const float inv = __expf(-(float)dh * 0.20503692772194388f);
    float cs, sn;
    sincosf(p * inv, &sn, &cs);
    const float o = (d < 64) ? (xn * cs - xp * sn) : (xn * cs + xp * sn);
    dst[(size_t)t * HID + idx] = (f16)o;
  }
}

// ------------------------------------------------- GEMM 128x128xBK64, double-buffered (kept for gemm_out_sk)
__device__ __forceinline__ void gemm_issue(const f16* __restrict__ A, const f16* __restrict__ Bt,
                                           char* As, char* Bs, int m0, int n0, int k0,
                                           int wave, int srow, int scol) {
#pragma unroll
  for (int i = 0; i < 4; ++i) {
    async16(A + (size_t)(m0 + 32 * i + srow) * 2048 + k0 + scol, As + 4096 * i + 1024 * wave);
    async16(Bt + (size_t)(n0 + 32 * i + srow) * 2048 + k0 + scol, Bs + 4096 * i + 1024 * wave);
  }
}

__device__ __forceinline__ void gemm_core_db(const f16* __restrict__ A, const f16* __restrict__ Bt,
                                             f16* As, f16* Bs, floatx4 (&acc)[4][4],
                                             int kbase, int klen) {
  const int tid = threadIdx.x;
  const int lane = tid & 63, wave = tid >> 6;
  const int m0 = blockIdx.y * 128, n0 = blockIdx.x * 128;
  const int mo = (wave >> 1) * 64, no = (wave & 1) * 64;
  const int cn = lane & 15, q16 = lane >> 4;
  const int srow = 8 * wave + (lane >> 3);
  const int scol = (lane & 7) * 8;
  gemm_issue(A, Bt, (char*)As, (char*)Bs, m0, n0, kbase, wave, srow, scol);
  int cur = 0;
  for (int k0 = kbase; k0 < kbase + klen; k0 += 64) {
    __syncthreads();
    if (k0 + 64 < kbase + klen)
      gemm_issue(A, Bt, (char*)(As + (cur ^ 1) * 8192), (char*)(Bs + (cur ^ 1) * 8192),
                 m0, n0, k0 + 64, wave, srow, scol);
    const f16* as = As + cur * 8192;
    const f16* bs = Bs + cur * 8192;
#pragma unroll
    for (int kk = 0; kk < 64; kk += 32) {
      half8 av[4], bv[4];
#pragma unroll
      for (int i = 0; i < 4; ++i) av[i] = *(const half8*)&as[(mo + i * 16 + cn) * 64 + kk + q16 * 8];
#pragma unroll
      for (int i = 0; i < 4; ++i) bv[i] = *(const half8*)&bs[(no + i * 16 + cn) * 64 + kk + q16 * 8];
#pragma unroll
      for (int i = 0; i < 4; ++i)
#pragma unroll
        for (int j = 0; j < 4; ++j)
          acc[i][j] = __builtin_amdgcn_mfma_f32_16x16x32_f16(av[i], bv[j], acc[i][j], 0, 0, 0);
    }
    cur ^= 1;
  }
}

// ================================================= 256^2 8-phase QKV GEMM (T2+T3+T4+T5)
// BM=BN=256, BK=64, 8 waves (2M x 4N), 512 threads, 128 KiB LDS double-buffer.
// LDS layout per buffer: A[256][64] f16 then B[256][64] f16, XOR-swizzled in 16B granules:
//   granule_stored(g, row) = g ^ (row & 7)   (achieved by pre-swizzling the GLOBAL source
//   column; global_load_lds dest stays linear: wave-uniform base + lane*16).
// Phase schedule per K-tile t (buffer pb = t&1):
//   P1: read A-mq0 (8x b128) + B-nq0 (4x b128) | stage B1(t+1)->pb^1 | lgkm0 bar MFMA Q00 bar
//   P2: read B-nq1 (4x b128)                   | stage A1(t+1)->pb^1 | lgkm0 bar MFMA Q01 bar
//   P3: read A-mq1 (8x b128)                   | stage B0(t+2)->pb   | lgkm0 bar MFMA Q10 bar
//   P4: (no reads)                             | stage A0(t+2)->pb, s_waitcnt vmcnt(4) | bar MFMA Q11 bar
// Region-retirement proof: B halves last read at P2, A halves at P3; every stage lands >=1
// barrier after its region's last read. vmcnt(4) exempts exactly {B0(t+2), A0(t+2)} and
// guarantees all of tile t+1 before its P1.
#define NKT 32

__device__ __forceinline__ void stage_half(const f16* __restrict__ src, int row0, int kcol,
                                           char* dst, int wv, int lane) {
  const int rsw = lane >> 3;                 // row-within-8
  const int csw = ((lane & 7) ^ rsw) << 3;   // pre-swizzled source column (elements)
#pragma unroll
  for (int L = 0; L < 2; ++L)
    async16(src + (size_t)(row0 + L * 64 + wv * 8 + rsw) * 2048 + kcol + csw,
            dst + (L * 64 + wv * 8) * 128);  // wave-uniform dest; HW adds lane*16
}

template <int MQ>
__device__ __forceinline__ void ld_a4(half8 (&a)[4][2], const f16* As, int wm, int cn, int q16) {
#pragma unroll
  for (int rf = 0; rf < 4; ++rf)
#pragma unroll
    for (int kh = 0; kh < 2; ++kh) {
      const int R = wm * 128 + MQ * 64 + rf * 16 + cn;
      a[rf][kh] = *(const half8*)&As[R * 64 + (((kh * 4 + q16) ^ (cn & 7)) << 3)];
    }
}

template <int NQ>
__device__ __forceinline__ void ld_b2(half8 (&b)[2][2], const f16* Bs, int wn, int cn, int q16) {
#pragma unroll
  for (int cf = 0; cf < 2; ++cf)
#pragma unroll
    for (int kh = 0; kh < 2; ++kh) {
      const int S = wn * 64 + NQ * 32 + cf * 16 + cn;
      b[cf][kh] = *(const half8*)&Bs[S * 64 + (((kh * 4 + q16) ^ (cn & 7)) << 3)];
    }
}

template <int MQ, int NQ>
__device__ __forceinline__ void mma16(floatx4 (&acc)[8][4], const half8 (&a)[4][2], const half8 (&b)[2][2]) {
#pragma unroll
  for (int kh = 0; kh < 2; ++kh)
#pragma unroll
    for (int rf = 0; rf < 4; ++rf)
#pragma unroll
      for (int cf = 0; cf < 2; ++cf)
        acc[MQ * 4 + rf][NQ * 2 + cf] = __builtin_amdgcn_mfma_f32_16x16x32_f16(
            a[rf][kh], b[cf][kh], acc[MQ * 4 + rf][NQ * 2 + cf], 0, 0, 0);
}

#define LGKM0() asm volatile("s_waitcnt lgkmcnt(0)" ::: "memory")
#define BAR()   __builtin_amdgcn_s_barrier()
#define PRIO(x) __builtin_amdgcn_s_setprio(x)
#define HBASE(p, isB, h) ((char*)lds + (p) * 65536 + (isB) * 32768 + (h) * 16384)

__global__ __launch_bounds__(512, 2) void gemm_qkv8(const f16* __restrict__ A,
                                                    const f16* __restrict__ B0_, const f16* __restrict__ B1_,
                                                    const f16* __restrict__ B2_,
                                                    f16* __restrict__ C0, f16* __restrict__ C1,
                                                    f16* __restrict__ C2) {
  __shared__ __align__(16) f16 lds[65536];  // 128 KiB: 2 buf x (A 256x64 + B 256x64)
  const int tid = threadIdx.x;
  const int lane = tid & 63, wv = tid >> 6;
  const int wm = wv >> 2, wn = wv & 3;
  const int q16 = lane >> 4, cn = lane & 15;
  const int z = blockIdx.z;
  const f16* Bt = (z == 0) ? B0_ : ((z == 1) ? B1_ : B2_);
  f16* C = (z == 0) ? C0 : ((z == 1) ? C1 : C2);
  const int m0 = blockIdx.y * 256, n0 = blockIdx.x * 256;

  floatx4 acc[8][4] = {};
  half8 a[4][2], b0[2][2], b1[2][2];

  // prologue: tile0 (4 halves) + first 2 halves of tile1; allow newest 4 loads in flight
  stage_half(A,  m0,       0,  HBASE(0, 0, 0), wv, lane);   // A0(0)
  stage_half(Bt, n0,       0,  HBASE(0, 1, 0), wv, lane);   // B0(0)
  stage_half(Bt, n0 + 128, 0,  HBASE(0, 1, 1), wv, lane);   // B1(0)
  stage_half(A,  m0 + 128, 0,  HBASE(0, 0, 1), wv, lane);   // A1(0)
  stage_half(Bt, n0,       64, HBASE(1, 1, 0), wv, lane);   // B0(1)
  stage_half(A,  m0,       64, HBASE(1, 0, 0), wv, lane);   // A0(1)
  asm volatile("s_waitcnt vmcnt(4)" ::: "memory");
  BAR();

  for (int t = 0; t < NKT; ++t) {
    const int pb = t & 1;
    const f16* As = lds + pb * 32768;
    const f16* Bs = As + 16384;
    // ---- P1
    ld_a4<0>(a, As, wm, cn, q16);
    ld_b2<0>(b0, Bs, wn, cn, q16);
    if (t + 1 < NKT) stage_half(Bt, n0 + 128, (t + 1) * 64, HBASE(pb ^ 1, 1, 1), wv, lane);
    LGKM0(); BAR();
    PRIO(1); mma16<0, 0>(acc, a, b0); PRIO(0);
    BAR();
    // ---- P2
    ld_b2<1>(b1, Bs, wn, cn, q16);
    if (t + 1 < NKT) stage_half(A, m0 + 128, (t + 1) * 64, HBASE(pb ^ 1, 0, 1), wv, lane);
    LGKM0(); BAR();
    PRIO(1); mma16<0, 1>(acc, a, b1); PRIO(0);
    BAR();
    // ---- P3
    ld_a4<1>(a, As, wm, cn, q16);
    if (t + 2 < NKT) stage_half(Bt, n0, (t + 2) * 64, HBASE(pb, 1, 0), wv, lane);
    LGKM0(); BAR();
    PRIO(1); mma16<1, 0>(acc, a, b0); PRIO(0);
    BAR();
    // ---- P4
    if (t + 2 < NKT) {
      stage_half(A, m0, (t + 2) * 64, HBASE(pb, 0, 0), wv, lane);
      asm volatile("s_waitcnt vmcnt(4)" ::: "memory");
    } else if (t == NKT - 2) {
      asm volatile("s_waitcnt vmcnt(0)" ::: "memory");
    }
    BAR();
    PRIO(1); mma16<1, 1>(acc, a, b1); PRIO(0);
    BAR();
  }

  // epilogue: C rows = m0 + wm*128 + i*16 + q16*4 + r, cols = n0 + wn*64 + j*16 + cn
  const int r0 = q16 * 4;
#pragma unroll
  for (int i = 0; i < 8; ++i)
#pragma unroll
    for (int j = 0; j < 4; ++j)
#pragma unroll
      for (int r = 0; r < 4; ++r)
        C[(size_t)(m0 + wm * 128 + i * 16 + r0 + r) * 2048 + n0 + wn * 64 + j * 16 + cn] =
            (f16)acc[i][j][r];
}

// split-K=2 attention-output GEMM: z picks K-half, writes fp32 partial
__global__ __launch_bounds__(256, 2) void gemm_out_sk(const f16* __restrict__ A, const f16* __restrict__ Bt,
                                                      float* __restrict__ P0, float* __restrict__ P1) {
  __shared__ __align__(16) f16 As[2 * 128 * 64];
  __shared__ __align__(16) f16 Bs[2 * 128 * 64];
  const int z = blockIdx.z;
  floatx4 acc[4][4] = {};
  gemm_core_db(A, Bt, As, Bs, acc, z * 1024, 1024);
  float* C = z ? P1 : P0;
  const int lane = threadIdx.x & 63, wave = threadIdx.x >> 6;
  const int mb = blockIdx.y * 128 + (wave >> 1) * 64;
  const int nb = blockIdx.x * 128 + (wave & 1) * 64;
  const int r0 = (lane >> 4) * 4, cn = lane & 15;
#pragma unroll
  for (int i = 0; i < 4; ++i)
#pragma unroll
    for (int j = 0; j < 4; ++j)
#pragma unroll
      for (int r = 0; r < 4; ++r)
        C[(size_t)(mb + i * 16 + r0 + r) * 2048 + nb + j * 16 + cn] = acc[i][j][r];
}

__global__ __launch_bounds__(256) void add_out(const float* __restrict__ P0, const float* __restrict__ P1,
                                               float* __restrict__ out) {
  const int i = (blockIdx.x * 256 + threadIdx.x) * 4;
  const float4 a = *(const float4*)(P0 + i);
  const float4 b = *(const float4*)(P1 + i);
  float4 o;
  o.x = a.x + b.x; o.y = a.y + b.y; o.z = a.z + b.z; o.w = a.w + b.w;
  *(float4*)(out + i) = o;
}

// ------------------------------------------------- dual flash attention v3: gate-select single-accumulator
__global__ __launch_bounds__(256, 2) void flash_kernel(const f16* __restrict__ Qg, const f16* __restrict__ Kg,
                                                       const f16* __restrict__ VTg, const float* __restrict__ gate,
                                                       f16* __restrict__ Oa) {
  __shared__ __align__(16) f16 Ks[2][64 * 128];    // [s][d]
  __shared__ __align__(16) f16 VTs[2][128 * 64];   // [d][s]
  __shared__ __align__(16) f16 Ps[4][16][72];      // wave-private, 144B stride: aligned + 2-way max

  const int tid = threadIdx.x;
  const int lane = tid & 63, wv = tid >> 6;
  const int q16 = lane >> 4, cn = lane & 15;
  const int r0 = q16 * 4;

  const int p = blockIdx.x;
  const int xcd = p & 7;
  const int idx = p >> 3;
  const int h = (xcd << 1) | (idx & 1);
  const int rest = idx >> 1;
  const int qt = (rest < 16) ? rest : 47 - rest;
  const int t0 = qt * 64;

  bool gbit[4];
#pragma unroll
  for (int r = 0; r < 4; ++r)
    gbit[r] = gate[(size_t)(t0 + wv * 16 + r0 + r) * NH + h] > 0.5f;

  half8 qa[4];
#pragma unroll
  for (int i = 0; i < 4; ++i)
    qa[i] = *(const half8*)(Qg + (size_t)(t0 + 16 * wv + cn) * HID + h * HD + 32 * i + q16 * 8);

#pragma unroll
  for (int i = 0; i < 4; ++i) {
    const int rk = 16 * i + 4 * wv + q16;
    async16(Kg + (size_t)rk * HID + h * HD + cn * 8, (char*)Ks[0] + 4096 * i + 1024 * wv);
    const int rv = 32 * i + 8 * wv + (lane >> 3);
    async16(VTg + (size_t)(h * HD + rv) * T_DIM + (lane & 7) * 8, (char*)VTs[0] + 4096 * i + 1024 * wv);
  }

  floatx4 og[8] = {};
  floatx4 lacc = {0.f, 0.f, 0.f, 0.f};
  float mg[4];
#pragma unroll
  for (int r = 0; r < 4; ++r) mg[r] = NEG_BIG;

  const half8 ones = {(f16)1, (f16)1, (f16)1, (f16)1, (f16)1, (f16)1, (f16)1, (f16)1};

  int cur = 0;
  for (int kt = 0; kt <= qt; ++kt) {
    const int s0 = kt * 64;
    __syncthreads();
    if (kt < qt) {
      const int sn = s0 + 64;
#pragma unroll
      for (int i = 0; i < 4; ++i) {
        const int rk = 16 * i + 4 * wv + q16;
        async16(Kg + (size_t)(sn + rk) * HID + h * HD + cn * 8, (char*)Ks[cur ^ 1] + 4096 * i + 1024 * wv);
        const int rv = 32 * i + 8 * wv + (lane >> 3);
        async16(VTg + (size_t)(h * HD + rv) * T_DIM + sn + (lane & 7) * 8, (char*)VTs[cur ^ 1] + 4096 * i + 1024 * wv);
      }
    }

    // S = Q K^T : wave wv owns rows [16wv, 16wv+16)
    floatx4 sacc[4] = {};
#pragma unroll
    for (int i = 0; i < 4; ++i)
#pragma unroll
      for (int nt = 0; nt < 4; ++nt) {
        half8 b = *(const half8*)&Ks[cur][(nt * 16 + cn) * 128 + 32 * i + q16 * 8];
        sacc[nt] = __builtin_amdgcn_mfma_f32_16x16x32_f16(qa[i], b, sacc[nt], 0, 0, 0);
      }

    const bool diag = (kt == qt);

    float pe[4][4];
#pragma unroll
    for (int nt = 0; nt < 4; ++nt)
#pragma unroll
      for (int r = 0; r < 4; ++r) {
        float x = sacc[nt][r] * SM_SCALE;
        if (diag && (s0 + nt * 16 + cn > t0 + wv * 16 + r0 + r)) x = NEG_BIG;
        pe[nt][r] = x;
      }

    float rmax[4];
#pragma unroll
    for (int r = 0; r < 4; ++r)
      rmax[r] = fmaxf(fmaxf(pe[0][r], pe[1][r]), fmaxf(pe[2][r], pe[3][r]));
#pragma unroll
    for (int off = 1; off < 16; off <<= 1)
#pragma unroll
      for (int r = 0; r < 4; ++r) rmax[r] = fmaxf(rmax[r], __shfl_xor(rmax[r], off, 64));

    float alpha[4];
#pragma unroll
    for (int r = 0; r < 4; ++r) {
      const float mn = fmaxf(mg[r], rmax[r]);
      alpha[r] = __expf(mg[r] - mn);
      mg[r] = mn;
    }
#pragma unroll
    for (int dt = 0; dt < 8; ++dt)
#pragma unroll
      for (int r = 0; r < 4; ++r) og[dt][r] *= alpha[r];
#pragma unroll
    for (int r = 0; r < 4; ++r) lacc[r] *= alpha[r];

    // exp, gate/window select, store P_sel (wave-private -> no barrier)
#pragma unroll
    for (int nt = 0; nt < 4; ++nt)
#pragma unroll
      for (int r = 0; r < 4; ++r) {
        const float e = __expf(pe[nt][r] - mg[r]);   // causal-masked -> 0
        const int tt = t0 + wv * 16 + r0 + r;
        const int s = s0 + nt * 16 + cn;
        const bool keep = gbit[r] || (tt - s < 128);
        Ps[wv][r0 + r][nt * 16 + cn] = keep ? (f16)e : (f16)0.f;
      }

    // PV + row-sum: A = own P_sel rows
#pragma unroll
    for (int kk = 0; kk < 64; kk += 32) {
      half8 a = *(const half8*)&Ps[wv][cn][kk + q16 * 8];
#pragma unroll
      for (int dt = 0; dt < 8; ++dt) {
        half8 b = *(const half8*)&VTs[cur][(dt * 16 + cn) * 64 + kk + q16 * 8];
        og[dt] = __builtin_amdgcn_mfma_f32_16x16x32_f16(a, b, og[dt], 0, 0, 0);
      }
      lacc = __builtin_amdgcn_mfma_f32_16x16x32_f16(a, ones, lacc, 0, 0, 0);
    }
    cur ^= 1;
  }

  // epilogue: normalize, store f16 (selection already baked into P)
#pragma unroll
  for (int dt = 0; dt < 8; ++dt)
#pragma unroll
    for (int r = 0; r < 4; ++r) {
      const float v = og[dt][r] / lacc[r];
      Oa[(size_t)(t0 + wv * 16 + r0 + r) * HID + h * HD + dt * 16 + cn] = (f16)v;
    }
}

// ------------------------------------------------------------------ host
extern "C" void kernel_launch(void* const* d_in, const int* in_sizes, int n_in,
                              void* d_out, int out_size, void* d_ws, size_t ws_size,
                              hipStream_t stream) {
  const float* hidden = (const float*)d_in[0];
  const int* pos = (const int*)d_in[1];
  const float* Wq = (const float*)d_in[2];
  const float* Wk = (const float*)d_in[3];
  const float* Wv = (const float*)d_in[4];
  const float* Wo = (const float*)d_in[5];
  const float* qw = (const float*)d_in[6];
  const float* kw = (const float*)d_in[7];

  char* ws = (char*)d_ws;
  const size_t MB = 1ull << 20;
  // Peak footprint 88.125 MB — identical to passing rounds 1/3/7.
  f16* WqT = (f16*)(ws + 0 * MB);         // 8 MB; reused as WoT after QKV
  f16* WkT = (f16*)(ws + 8 * MB);         // 8 MB; dead after QKV
  f16* WvT = (f16*)(ws + 16 * MB);        // 8 MB; dead after QKV
  f16* hidh = (f16*)(ws + 24 * MB);       // 8 MB; dead after QKV
  f16* q_raw = (f16*)(ws + 32 * MB);      // 8 MB f16; reused as attn after norm
  f16* k_raw = (f16*)(ws + 48 * MB);      // 8 MB f16; reused as vT after norm
  f16* v_h = (f16*)(ws + 64 * MB);        // 8 MB
  f16* q_h = (f16*)(ws + 72 * MB);        // 8 MB; dead after flash
  f16* k_h = (f16*)(ws + 80 * MB);        // 8 MB; dead after flash
  float* gate = (float*)(ws + 88 * MB);   // 128 KB
  f16* WoT = WqT;
  f16* attn = q_raw;
  f16* vT = k_raw;
  float* P0 = (float*)(ws + 8 * MB);      // 16 MB over WkT+WvT (dead at use)
  float* P1 = (float*)(ws + 72 * MB);     // 16 MB over q_h+k_h (dead at use)

  dim3 tb(32, 8);
  transpose_all<<<dim3(64, 64, 3), tb, 0, stream>>>(Wq, Wk, Wv, WqT, WkT, WvT);
  convert_f32_f16<<<4096, 256, 0, stream>>>(hidden, hidh);
  gate_kernel<<<2048, 256, 0, stream>>>(hidden, Wq, gate);
  gemm_qkv8<<<dim3(8, 8, 3), 512, 0, stream>>>(hidh, WqT, WkT, WvT, q_raw, k_raw, v_h);
  transpose_w<<<dim3(64, 64), tb, 0, stream>>>(Wo, 2048, WoT);
  norm_rope2<<<4096, 256, 0, stream>>>(q_raw, k_raw, qw, kw, pos, q_h, k_h);
  transpose_h<<<dim3(64, 64), tb, 0, stream>>>(v_h, vT);
  flash_kernel<<<512, 256, 0, stream>>>(q_h, k_h, vT, gate, attn);
  gemm_out_sk<<<dim3(16, 16, 2), 256, 0, stream>>>(attn, WoT, P0, P1);
  add_out<<<4096, 256, 0, stream>>>(P0, P1, (float*)d_out);
}

// Round 2
// 346.735 us; speedup vs baseline: 1.1788x; 1.0671x over previous
//
#include <hip/hip_runtime.h>

typedef _Float16 f16;
typedef __attribute__((ext_vector_type(8))) _Float16 half8;
typedef __attribute__((ext_vector_type(4))) _Float16 half4v;
typedef __attribute__((ext_vector_type(4))) float floatx4;

#define T_DIM 2048
#define HID   2048
#define NH    16
#define HD    128
#define QG_LD 2064
#define SM_SCALE 0.08838834764831845f   // 1/sqrt(128)
#define NEG_BIG  -1e30f

// ---------------------------------------------------------------- async copy
__device__ __forceinline__ void async16(const void* g, void* l) {
  __builtin_amdgcn_global_load_lds((const __attribute__((address_space(1))) void*)g,
                                   (__attribute__((address_space(3))) void*)l, 16, 0, 0);
}

// ------------------------------------------------- fused QKV weight transpose (z selects)
__global__ __launch_bounds__(256) void transpose_all(const float* __restrict__ Wq,
                                                     const float* __restrict__ Wk,
                                                     const float* __restrict__ Wv,
                                                     f16* __restrict__ WqT, f16* __restrict__ WkT,
                                                     f16* __restrict__ WvT) {
  __shared__ float tile[32][33];
  const int z = blockIdx.z;
  const float* src = (z == 0) ? Wq : ((z == 1) ? Wk : Wv);
  const int ld = (z == 0) ? QG_LD : 2048;
  f16* dst = (z == 0) ? WqT : ((z == 1) ? WkT : WvT);
  const int bx = blockIdx.x * 32, by = blockIdx.y * 32;
  const int tx = threadIdx.x, ty = threadIdx.y;
#pragma unroll
  for (int i = 0; i < 4; ++i)
    tile[ty + 8 * i][tx] = src[(size_t)(by + ty + 8 * i) * ld + bx + tx];
  __syncthreads();
#pragma unroll
  for (int i = 0; i < 4; ++i)
    dst[(size_t)(bx + ty + 8 * i) * HID + by + tx] = (f16)tile[tx][ty + 8 * i];
}

// ------------------------------------------------- fp32 -> fp16 transpose (Wo)
__global__ __launch_bounds__(256) void transpose_w(const float* __restrict__ src, int src_ld,
                                                   f16* __restrict__ dst) {
  __shared__ float tile[32][33];
  const int bx = blockIdx.x * 32, by = blockIdx.y * 32;
  const int tx = threadIdx.x, ty = threadIdx.y;
#pragma unroll
  for (int i = 0; i < 4; ++i)
    tile[ty + 8 * i][tx] = src[(size_t)(by + ty + 8 * i) * src_ld + bx + tx];
  __syncthreads();
#pragma unroll
  for (int i = 0; i < 4; ++i)
    dst[(size_t)(bx + ty + 8 * i) * HID + by + tx] = (f16)tile[tx][ty + 8 * i];
}

// ------------------------------------------------- fp16 -> fp16 transpose (V)
__global__ __launch_bounds__(256) void transpose_h(const f16* __restrict__ src, f16* __restrict__ dst) {
  __shared__ f16 tile[32][33];
  const int bx = blockIdx.x * 32, by = blockIdx.y * 32;
  const int tx = threadIdx.x, ty = threadIdx.y;
#pragma unroll
  for (int i = 0; i < 4; ++i)
    tile[ty + 8 * i][tx] = src[(size_t)(by + ty + 8 * i) * T_DIM + bx + tx];
  __syncthreads();
#pragma unroll
  for (int i = 0; i < 4; ++i)
    dst[(size_t)(bx + ty + 8 * i) * T_DIM + by + tx] = tile[tx][ty + 8 * i];
}

// ------------------------------------------------- fp32 -> fp16 convert (hidden)
__global__ __launch_bounds__(256) void convert_f32_f16(const float* __restrict__ src, f16* __restrict__ dst) {
  const int i = (blockIdx.x * 256 + threadIdx.x) * 4;
  const float4 v = *(const float4*)(src + i);
  half4v o;
  o.x = (f16)v.x; o.y = (f16)v.y; o.z = (f16)v.z; o.w = (f16)v.w;
  *(half4v*)(dst + i) = o;
}

// ------------------------------------------------- gate: fp64 dot, sign only matters
__global__ __launch_bounds__(256) void gate_kernel(const float* __restrict__ hidden,
                                                   const float* __restrict__ Wq,
                                                   float* __restrict__ gate) {
  __shared__ double red[256][16];
  const int t = blockIdx.x, tid = threadIdx.x;
  double sums[16];
#pragma unroll
  for (int h2 = 0; h2 < 16; ++h2) sums[h2] = 0.0;
  const float* hrow = hidden + (size_t)t * HID;
  for (int k = tid; k < HID; k += 256) {
    const double hv = (double)hrow[k];
    const float* wr = Wq + (size_t)k * QG_LD + 2048;
#pragma unroll
    for (int h2 = 0; h2 < 16; ++h2) sums[h2] += hv * (double)wr[h2];
  }
#pragma unroll
  for (int h2 = 0; h2 < 16; ++h2) red[tid][h2] = sums[h2];
  __syncthreads();
  for (int st = 128; st > 0; st >>= 1) {
    if (tid < st) {
#pragma unroll
      for (int h2 = 0; h2 < 16; ++h2) red[tid][h2] += red[tid + st][h2];
    }
    __syncthreads();
  }
  if (tid < 16) gate[(size_t)t * 16 + tid] = (red[0][tid] > 0.0) ? 1.f : 0.f;
}

// ------------------------------------------------- RMSNorm(full 2048) + RoPE (q & k fused, f16 in)
__global__ __launch_bounds__(256) void norm_rope2(const f16* __restrict__ qsrc, const f16* __restrict__ ksrc,
                                                  const float* __restrict__ qw, const float* __restrict__ kw,
                                                  const int* __restrict__ pos,
                                                  f16* __restrict__ qdst, f16* __restrict__ kdst) {
  __shared__ float row[2048];
  __shared__ float red[256];
  const int t = blockIdx.x & 2047, sel = blockIdx.x >> 11, tid = threadIdx.x;
  const f16* s = (sel ? ksrc : qsrc) + (size_t)t * HID;
  const float* w = sel ? kw : qw;
  f16* dst = sel ? kdst : qdst;
  float ss = 0.f;
#pragma unroll
  for (int e = 0; e < 8; ++e) {
    float v = (float)s[tid + 256 * e];
    row[tid + 256 * e] = v;
    ss += v * v;
  }
  red[tid] = ss;
  __syncthreads();
  for (int st = 128; st > 0; st >>= 1) {
    if (tid < st) red[tid] += red[tid + st];
    __syncthreads();
  }
  const float scl = rsqrtf(red[0] * (1.f / 2048.f) + 1e-6f);
  const float p = (float)pos[t];
#pragma unroll
  for (int e = 0; e < 8; ++e) {
    const int idx = tid + 256 * e;
    const int d = idx & 127;
    const int dh = d & 63;
    const int pidx = (d < 64) ? idx + 64 : idx - 64;
    const float xn = row[idx] * scl * w[idx];
    const float xp = row[pidx] * scl * w[pidx];
    const float inv = __expf(-(float)dh * 0.20503692772194388f);
    float cs, sn;
    sincosf(p * inv, &sn, &cs);
    const float o = (d < 64) ? (xn * cs - xp * sn) : (xn * cs + xp * sn);
    dst[(size_t)t * HID + idx] = (f16)o;
  }
}

// ------------------------------------------------- GEMM 128x128xBK64, double-buffered (kept for gemm_out_sk)
__device__ __forceinline__ void gemm_issue(const f16* __restrict__ A, const f16* __restrict__ Bt,
                                           char* As, char* Bs, int m0, int n0, int k0,
                                           int wave, int srow, int scol) {
#pragma unroll
  for (int i = 0; i < 4; ++i) {
    async16(A + (size_t)(m0 + 32 * i + srow) * 2048 + k0 + scol, As + 4096 * i + 1024 * wave);
    async16(Bt + (size_t)(n0 + 32 * i + srow) * 2048 + k0 + scol, Bs + 4096 * i + 1024 * wave);
  }
}

__device__ __forceinline__ void gemm_core_db(const f16* __restrict__ A, const f16* __restrict__ Bt,
                                             f16* As, f16* Bs, floatx4 (&acc)[4][4],
                                             int kbase, int klen) {
  const int tid = threadIdx.x;
  const int lane = tid & 63, wave = tid >> 6;
  const int m0 = blockIdx.y * 128, n0 = blockIdx.x * 128;
  const int mo = (wave >> 1) * 64, no = (wave & 1) * 64;
  const int cn = lane & 15, q16 = lane >> 4;
  const int srow = 8 * wave + (lane >> 3);
  const int scol = (lane & 7) * 8;
  gemm_issue(A, Bt, (char*)As, (char*)Bs, m0, n0, kbase, wave, srow, scol);
  int cur = 0;
  for (int k0 = kbase; k0 < kbase + klen; k0 += 64) {
    __syncthreads();
    if (k0 + 64 < kbase + klen)
      gemm_issue(A, Bt, (char*)(As + (cur ^ 1) * 8192), (char*)(Bs + (cur ^ 1) * 8192),
                 m0, n0, k0 + 64, wave, srow, scol);
    const f16* as = As + cur * 8192;
    const f16* bs = Bs + cur * 8192;
#pragma unroll
    for (int kk = 0; kk < 64; kk += 32) {
      half8 av[4], bv[4];
#pragma unroll
      for (int i = 0; i < 4; ++i) av[i] = *(const half8*)&as[(mo + i * 16 + cn) * 64 + kk + q16 * 8];
#pragma unroll
      for (int i = 0; i < 4; ++i) bv[i] = *(const half8*)&bs[(no + i * 16 + cn) * 64 + kk + q16 * 8];
#pragma unroll
      for (int i = 0; i < 4; ++i)
#pragma unroll
        for (int j = 0; j < 4; ++j)
          acc[i][j] = __builtin_amdgcn_mfma_f32_16x16x32_f16(av[i], bv[j], acc[i][j], 0, 0, 0);
    }
    cur ^= 1;
  }
}

// ================================================= 256^2 8-phase QKV GEMM (T2+T3+T4+T5)
#define NKT 32

__device__ __forceinline__ void stage_half(const f16* __restrict__ src, int row0, int kcol,
                                           char* dst, int wv, int lane) {
  const int rsw = lane >> 3;                 // row-within-8
  const int csw = ((lane & 7) ^ rsw) << 3;   // pre-swizzled source column (elements)
#pragma unroll
  for (int L = 0; L < 2; ++L)
    async16(src + (size_t)(row0 + L * 64 + wv * 8 + rsw) * 2048 + kcol + csw,
            dst + (L * 64 + wv * 8) * 128);  // wave-uniform dest; HW adds lane*16
}

template <int MQ>
__device__ __forceinline__ void ld_a4(half8 (&a)[4][2], const f16* As, int wm, int cn, int q16) {
#pragma unroll
  for (int rf = 0; rf < 4; ++rf)
#pragma unroll
    for (int kh = 0; kh < 2; ++kh) {
      const int R = wm * 128 + MQ * 64 + rf * 16 + cn;
      a[rf][kh] = *(const half8*)&As[R * 64 + (((kh * 4 + q16) ^ (cn & 7)) << 3)];
    }
}

template <int NQ>
__device__ __forceinline__ void ld_b2(half8 (&b)[2][2], const f16* Bs, int wn, int cn, int q16) {
#pragma unroll
  for (int cf = 0; cf < 2; ++cf)
#pragma unroll
    for (int kh = 0; kh < 2; ++kh) {
      const int S = wn * 64 + NQ * 32 + cf * 16 + cn;
      b[cf][kh] = *(const half8*)&Bs[S * 64 + (((kh * 4 + q16) ^ (cn & 7)) << 3)];
    }
}

template <int MQ, int NQ>
__device__ __forceinline__ void mma16(floatx4 (&acc)[8][4], const half8 (&a)[4][2], const half8 (&b)[2][2]) {
#pragma unroll
  for (int kh = 0; kh < 2; ++kh)
#pragma unroll
    for (int rf = 0; rf < 4; ++rf)
#pragma unroll
      for (int cf = 0; cf < 2; ++cf)
        acc[MQ * 4 + rf][NQ * 2 + cf] = __builtin_amdgcn_mfma_f32_16x16x32_f16(
            a[rf][kh], b[cf][kh], acc[MQ * 4 + rf][NQ * 2 + cf], 0, 0, 0);
}

#define LGKM0() asm volatile("s_waitcnt lgkmcnt(0)" ::: "memory")
#define BAR()   __builtin_amdgcn_s_barrier()
#define PRIO(x) __builtin_amdgcn_s_setprio(x)
#define HBASE(p, isB, h) ((char*)lds + (p) * 65536 + (isB) * 32768 + (h) * 16384)

__global__ __launch_bounds__(512, 2) void gemm_qkv8(const f16* __restrict__ A,
                                                    const f16* __restrict__ B0_, const f16* __restrict__ B1_,
                                                    const f16* __restrict__ B2_,
                                                    f16* __restrict__ C0, f16* __restrict__ C1,
                                                    f16* __restrict__ C2) {
  __shared__ __align__(16) f16 lds[65536];  // 128 KiB: 2 buf x (A 256x64 + B 256x64)
  const int tid = threadIdx.x;
  const int lane = tid & 63, wv = tid >> 6;
  const int wm = wv >> 2, wn = wv & 3;
  const int q16 = lane >> 4, cn = lane & 15;
  const int z = blockIdx.z;
  const f16* Bt = (z == 0) ? B0_ : ((z == 1) ? B1_ : B2_);
  f16* C = (z == 0) ? C0 : ((z == 1) ? C1 : C2);
  const int m0 = blockIdx.y * 256, n0 = blockIdx.x * 256;

  floatx4 acc[8][4] = {};
  half8 a[4][2], b0[2][2], b1[2][2];

  // prologue: tile0 (4 halves) + first 2 halves of tile1; allow newest 4 loads in flight
  stage_half(A,  m0,       0,  HBASE(0, 0, 0), wv, lane);   // A0(0)
  stage_half(Bt, n0,       0,  HBASE(0, 1, 0), wv, lane);   // B0(0)
  stage_half(Bt, n0 + 128, 0,  HBASE(0, 1, 1), wv, lane);   // B1(0)
  stage_half(A,  m0 + 128, 0,  HBASE(0, 0, 1), wv, lane);   // A1(0)
  stage_half(Bt, n0,       64, HBASE(1, 1, 0), wv, lane);   // B0(1)
  stage_half(A,  m0,       64, HBASE(1, 0, 0), wv, lane);   // A0(1)
  asm volatile("s_waitcnt vmcnt(4)" ::: "memory");
  BAR();

  for (int t = 0; t < NKT; ++t) {
    const int pb = t & 1;
    const f16* As = lds + pb * 32768;
    const f16* Bs = As + 16384;
    // ---- P1
    ld_a4<0>(a, As, wm, cn, q16);
    ld_b2<0>(b0, Bs, wn, cn, q16);
    if (t + 1 < NKT) stage_half(Bt, n0 + 128, (t + 1) * 64, HBASE(pb ^ 1, 1, 1), wv, lane);
    LGKM0(); BAR();
    PRIO(1); mma16<0, 0>(acc, a, b0); PRIO(0);
    BAR();
    // ---- P2
    ld_b2<1>(b1, Bs, wn, cn, q16);
    if (t + 1 < NKT) stage_half(A, m0 + 128, (t + 1) * 64, HBASE(pb ^ 1, 0, 1), wv, lane);
    LGKM0(); BAR();
    PRIO(1); mma16<0, 1>(acc, a, b1); PRIO(0);
    BAR();
    // ---- P3
    ld_a4<1>(a, As, wm, cn, q16);
    if (t + 2 < NKT) stage_half(Bt, n0, (t + 2) * 64, HBASE(pb, 1, 0), wv, lane);
    LGKM0(); BAR();
    PRIO(1); mma16<1, 0>(acc, a, b0); PRIO(0);
    BAR();
    // ---- P4
    if (t + 2 < NKT) {
      stage_half(A, m0, (t + 2) * 64, HBASE(pb, 0, 0), wv, lane);
      asm volatile("s_waitcnt vmcnt(4)" ::: "memory");
    } else if (t == NKT - 2) {
      asm volatile("s_waitcnt vmcnt(0)" ::: "memory");
    }
    BAR();
    PRIO(1); mma16<1, 1>(acc, a, b1); PRIO(0);
    BAR();
  }

  // epilogue
  const int r0 = q16 * 4;
#pragma unroll
  for (int i = 0; i < 8; ++i)
#pragma unroll
    for (int j = 0; j < 4; ++j)
#pragma unroll
      for (int r = 0; r < 4; ++r)
        C[(size_t)(m0 + wm * 128 + i * 16 + r0 + r) * 2048 + n0 + wn * 64 + j * 16 + cn] =
            (f16)acc[i][j][r];
}

// split-K=2 attention-output GEMM: z picks K-half, writes fp32 partial
__global__ __launch_bounds__(256, 2) void gemm_out_sk(const f16* __restrict__ A, const f16* __restrict__ Bt,
                                                      float* __restrict__ P0, float* __restrict__ P1) {
  __shared__ __align__(16) f16 As[2 * 128 * 64];
  __shared__ __align__(16) f16 Bs[2 * 128 * 64];
  const int z = blockIdx.z;
  floatx4 acc[4][4] = {};
  gemm_core_db(A, Bt, As, Bs, acc, z * 1024, 1024);
  float* C = z ? P1 : P0;
  const int lane = threadIdx.x & 63, wave = threadIdx.x >> 6;
  const int mb = blockIdx.y * 128 + (wave >> 1) * 64;
  const int nb = blockIdx.x * 128 + (wave & 1) * 64;
  const int r0 = (lane >> 4) * 4, cn = lane & 15;
#pragma unroll
  for (int i = 0; i < 4; ++i)
#pragma unroll
    for (int j = 0; j < 4; ++j)
#pragma unroll
      for (int r = 0; r < 4; ++r)
        C[(size_t)(mb + i * 16 + r0 + r) * 2048 + nb + j * 16 + cn] = acc[i][j][r];
}

__global__ __launch_bounds__(256) void add_out(const float* __restrict__ P0, const float* __restrict__ P1,
                                               float* __restrict__ out) {
  const int i = (blockIdx.x * 256 + threadIdx.x) * 4;
  const float4 a = *(const float4*)(P0 + i);
  const float4 b = *(const float4*)(P1 + i);
  float4 o;
  o.x = a.x + b.x; o.y = a.y + b.y; o.z = a.z + b.z; o.w = a.w + b.w;
  *(float4*)(out + i) = o;
}

// ------------------------------------------------- dual flash attention v4: XOR-swizzled K/V LDS
// Ks [64][128] f16 (256B rows) and VTs [128][64] f16 (128B rows) were read with 16 distinct
// rows per 16-lane group at the SAME 16B granule -> bank-quad serialization (2.19e7 conflicts).
// Fix (rule #21, both-sides): global_load_lds dest stays linear; the GLOBAL source column is
// pre-swizzled by granule ^= (row & 7); the ds_read applies the same XOR. Bit-identical data.
__global__ __launch_bounds__(256, 2) void flash_kernel(const f16* __restrict__ Qg, const f16* __restrict__ Kg,
                                                       const f16* __restrict__ VTg, const float* __restrict__ gate,
                                                       f16* __restrict__ Oa) {
  __shared__ __align__(16) f16 Ks[2][64 * 128];    // [s][d], granule-swizzled
  __shared__ __align__(16) f16 VTs[2][128 * 64];   // [d][s], granule-swizzled
  __shared__ __align__(16) f16 Ps[4][16][72];      // wave-private, 144B stride

  const int tid = threadIdx.x;
  const int lane = tid & 63, wv = tid >> 6;
  const int q16 = lane >> 4, cn = lane & 15;
  const int r0 = q16 * 4;

  const int p = blockIdx.x;
  const int xcd = p & 7;
  const int idx = p >> 3;
  const int h = (xcd << 1) | (idx & 1);
  const int rest = idx >> 1;
  const int qt = (rest < 16) ? rest : 47 - rest;
  const int t0 = qt * 64;

  bool gbit[4];
#pragma unroll
  for (int r = 0; r < 4; ++r)
    gbit[r] = gate[(size_t)(t0 + wv * 16 + r0 + r) * NH + h] > 0.5f;

  half8 qa[4];
#pragma unroll
  for (int i = 0; i < 4; ++i)
    qa[i] = *(const half8*)(Qg + (size_t)(t0 + 16 * wv + cn) * HID + h * HD + 32 * i + q16 * 8);

#pragma unroll
  for (int i = 0; i < 4; ++i) {
    const int rk = 16 * i + 4 * wv + q16;
    async16(Kg + (size_t)rk * HID + h * HD + ((cn ^ (rk & 7)) << 3), (char*)Ks[0] + 4096 * i + 1024 * wv);
    const int rv = 32 * i + 8 * wv + (lane >> 3);
    async16(VTg + (size_t)(h * HD + rv) * T_DIM + (((lane & 7) ^ (lane >> 3)) << 3),
            (char*)VTs[0] + 4096 * i + 1024 * wv);
  }

  floatx4 og[8] = {};
  floatx4 lacc = {0.f, 0.f, 0.f, 0.f};
  float mg[4];
#pragma unroll
  for (int r = 0; r < 4; ++r) mg[r] = NEG_BIG;

  const half8 ones = {(f16)1, (f16)1, (f16)1, (f16)1, (f16)1, (f16)1, (f16)1, (f16)1};

  int cur = 0;
  for (int kt = 0; kt <= qt; ++kt) {
    const int s0 = kt * 64;
    __syncthreads();
    if (kt < qt) {
      const int sn = s0 + 64;
#pragma unroll
      for (int i = 0; i < 4; ++i) {
        const int rk = 16 * i + 4 * wv + q16;
        async16(Kg + (size_t)(sn + rk) * HID + h * HD + ((cn ^ (rk & 7)) << 3),
                (char*)Ks[cur ^ 1] + 4096 * i + 1024 * wv);
        const int rv = 32 * i + 8 * wv + (lane >> 3);
        async16(VTg + (size_t)(h * HD + rv) * T_DIM + sn + (((lane & 7) ^ (lane >> 3)) << 3),
                (char*)VTs[cur ^ 1] + 4096 * i + 1024 * wv);
      }
    }

    // S = Q K^T : wave wv owns rows [16wv, 16wv+16)
    floatx4 sacc[4] = {};
    PRIO(1);
#pragma unroll
    for (int i = 0; i < 4; ++i)
#pragma unroll
      for (int nt = 0; nt < 4; ++nt) {
        half8 b = *(const half8*)&Ks[cur][(nt * 16 + cn) * 128 + (((4 * i + q16) ^ (cn & 7)) << 3)];
        sacc[nt] = __builtin_amdgcn_mfma_f32_16x16x32_f16(qa[i], b, sacc[nt], 0, 0, 0);
      }
    PRIO(0);

    const bool diag = (kt == qt);

    float pe[4][4];
#pragma unroll
    for (int nt = 0; nt < 4; ++nt)
#pragma unroll
      for (int r = 0; r < 4; ++r) {
        float x = sacc[nt][r] * SM_SCALE;
        if (diag && (s0 + nt * 16 + cn > t0 + wv * 16 + r0 + r)) x = NEG_BIG;
        pe[nt][r] = x;
      }

    float rmax[4];
#pragma unroll
    for (int r = 0; r < 4; ++r)
      rmax[r] = fmaxf(fmaxf(pe[0][r], pe[1][r]), fmaxf(pe[2][r], pe[3][r]));
#pragma unroll
    for (int off = 1; off < 16; off <<= 1)
#pragma unroll
      for (int r = 0; r < 4; ++r) rmax[r] = fmaxf(rmax[r], __shfl_xor(rmax[r], off, 64));

    float alpha[4];
#pragma unroll
    for (int r = 0; r < 4; ++r) {
      const float mn = fmaxf(mg[r], rmax[r]);
      alpha[r] = __expf(mg[r] - mn);
      mg[r] = mn;
    }
#pragma unroll
    for (int dt = 0; dt < 8; ++dt)
#pragma unroll
      for (int r = 0; r < 4; ++r) og[dt][r] *= alpha[r];
#pragma unroll
    for (int r = 0; r < 4; ++r) lacc[r] *= alpha[r];

    // exp, gate/window select, store P_sel (wave-private -> no barrier)
#pragma unroll
    for (int nt = 0; nt < 4; ++nt)
#pragma unroll
      for (int r = 0; r < 4; ++r) {
        const float e = __expf(pe[nt][r] - mg[r]);   // causal-masked -> 0
        const int tt = t0 + wv * 16 + r0 + r;
        const int s = s0 + nt * 16 + cn;
        const bool keep = gbit[r] || (tt - s < 128);
        Ps[wv][r0 + r][nt * 16 + cn] = keep ? (f16)e : (f16)0.f;
      }

    // PV + row-sum: A = own P_sel rows
    PRIO(1);
#pragma unroll
    for (int kk = 0; kk < 64; kk += 32) {
      half8 a = *(const half8*)&Ps[wv][cn][kk + q16 * 8];
#pragma unroll
      for (int dt = 0; dt < 8; ++dt) {
        half8 b = *(const half8*)&VTs[cur][(dt * 16 + cn) * 64 + ((((kk >> 3) + q16) ^ (cn & 7)) << 3)];
        og[dt] = __builtin_amdgcn_mfma_f32_16x16x32_f16(a, b, og[dt], 0, 0, 0);
      }
      lacc = __builtin_amdgcn_mfma_f32_16x16x32_f16(a, ones, lacc, 0, 0, 0);
    }
    PRIO(0);
    cur ^= 1;
  }

  // epilogue: normalize, store f16 (selection already baked into P)
#pragma unroll
  for (int dt = 0; dt < 8; ++dt)
#pragma unroll
    for (int r = 0; r < 4; ++r) {
      const float v = og[dt][r] / lacc[r];
      Oa[(size_t)(t0 + wv * 16 + r0 + r) * HID + h * HD + dt * 16 + cn] = (f16)v;
    }
}

// ------------------------------------------------------------------ host
extern "C" void kernel_launch(void* const* d_in, const int* in_sizes, int n_in,
                              void* d_out, int out_size, void* d_ws, size_t ws_size,
                              hipStream_t stream) {
  const float* hidden = (const float*)d_in[0];
  const int* pos = (const int*)d_in[1];
  const float* Wq = (const float*)d_in[2];
  const float* Wk = (const float*)d_in[3];
  const float* Wv = (const float*)d_in[4];
  const float* Wo = (const float*)d_in[5];
  const float* qw = (const float*)d_in[6];
  const float* kw = (const float*)d_in[7];

  char* ws = (char*)d_ws;
  const size_t MB = 1ull << 20;
  // Peak footprint 88.125 MB — identical to passing rounds 1/3/7.
  f16* WqT = (f16*)(ws + 0 * MB);         // 8 MB; reused as WoT after QKV
  f16* WkT = (f16*)(ws + 8 * MB);         // 8 MB; dead after QKV
  f16* WvT = (f16*)(ws + 16 * MB);        // 8 MB; dead after QKV
  f16* hidh = (f16*)(ws + 24 * MB);       // 8 MB; dead after QKV
  f16* q_raw = (f16*)(ws + 32 * MB);      // 8 MB f16; reused as attn after norm
  f16* k_raw = (f16*)(ws + 48 * MB);      // 8 MB f16; reused as vT after norm
  f16* v_h = (f16*)(ws + 64 * MB);        // 8 MB
  f16* q_h = (f16*)(ws + 72 * MB);        // 8 MB; dead after flash
  f16* k_h = (f16*)(ws + 80 * MB);        // 8 MB; dead after flash
  float* gate = (float*)(ws + 88 * MB);   // 128 KB
  f16* WoT = WqT;
  f16* attn = q_raw;
  f16* vT = k_raw;
  float* P0 = (float*)(ws + 8 * MB);      // 16 MB over WkT+WvT (dead at use)
  float* P1 = (float*)(ws + 72 * MB);     // 16 MB over q_h+k_h (dead at use)

  dim3 tb(32, 8);
  transpose_all<<<dim3(64, 64, 3), tb, 0, stream>>>(Wq, Wk, Wv, WqT, WkT, WvT);
  convert_f32_f16<<<4096, 256, 0, stream>>>(hidden, hidh);
  gate_kernel<<<2048, 256, 0, stream>>>(hidden, Wq, gate);
  gemm_qkv8<<<dim3(8, 8, 3), 512, 0, stream>>>(hidh, WqT, WkT, WvT, q_raw, k_raw, v_h);
  transpose_w<<<dim3(64, 64), tb, 0, stream>>>(Wo, 2048, WoT);
  norm_rope2<<<4096, 256, 0, stream>>>(q_raw, k_raw, qw, kw, pos, q_h, k_h);
  transpose_h<<<dim3(64, 64), tb, 0, stream>>>(v_h, vT);
  flash_kernel<<<512, 256, 0, stream>>>(q_h, k_h, vT, gate, attn);
  gemm_out_sk<<<dim3(16, 16, 2), 256, 0, stream>>>(attn, WoT, P0, P1);
  add_out<<<4096, 256, 0, stream>>>(P0, P1, (float*)d_out);
}